// Round 2
// baseline (716.419 us; speedup 1.0000x reference)
//
#include <hip/hip_runtime.h>

// Problem constants (fixed by reference)
#define CCH   128      // channels
#define NF    512      // node_feats row = C + 3C
#define OUTF  1408     // 2C + 3*3C
#define RDIM  8

#define INV_SQRT8  0.35355339059327373f
#define INV_SQRT10 0.31622776601683794f
#define SQRT3      1.7320508075688772f

__device__ __forceinline__ float silu(float x) {
    return x / (1.0f + __expf(-x));
}

// RNE float -> bf16 bits (inputs are finite randn-scale)
__device__ __forceinline__ unsigned int f2bf_bits(float f) {
    unsigned int u = __float_as_uint(f);
    u = (u + 0x7fffu + ((u >> 16) & 1u)) >> 16;
    return u & 0xffffu;
}
__device__ __forceinline__ float bflo(unsigned int u) { return __uint_as_float(u << 16); }
__device__ __forceinline__ float bfhi(unsigned int u) { return __uint_as_float(u & 0xffff0000u); }

// ---------------- CSR build ----------------
__global__ void k_zero(int* __restrict__ p, int n) {
    int i = blockIdx.x * 256 + threadIdx.x;
    if (i < n) p[i] = 0;
}

__global__ void k_hist(const int* __restrict__ recv, int* __restrict__ counts, int E) {
    int i = blockIdx.x * 256 + threadIdx.x;
    if (i < E) atomicAdd(&counts[recv[i]], 1);
}

// single-block exclusive scan over n, 1024 threads, wave-shuffle based
__global__ void k_scan(const int* __restrict__ counts, int* __restrict__ offsets,
                       int* __restrict__ cursor, int n) {
    __shared__ int wsum[16];
    int t = threadIdx.x;
    int lane = t & 63, wid = t >> 6;
    int carry = 0;
    for (int base = 0; base < n; base += 1024) {
        int i = base + t;
        int x = (i < n) ? counts[i] : 0;
        // inclusive wave scan
        int s = x;
        #pragma unroll
        for (int off = 1; off < 64; off <<= 1) {
            int v = __shfl_up(s, off, 64);
            if (lane >= off) s += v;
        }
        if (lane == 63) wsum[wid] = s;
        __syncthreads();
        if (wid == 0) {
            int v = (lane < 16) ? wsum[lane] : 0;
            #pragma unroll
            for (int off = 1; off < 16; off <<= 1) {
                int u = __shfl_up(v, off, 64);
                if (lane >= off) v += u;
            }
            if (lane < 16) wsum[lane] = v;
        }
        __syncthreads();
        int excl_wave = (wid > 0) ? wsum[wid - 1] : 0;
        int incl = s + excl_wave;
        if (i < n) {
            int ex = carry + incl - x;
            offsets[i] = ex;
            cursor[i]  = ex;
        }
        carry += wsum[15];
        __syncthreads();
    }
    if (t == 0) offsets[n] = carry;
}

__global__ void k_perm(const int* __restrict__ recv, int* __restrict__ cursor,
                       int* __restrict__ perm, int E) {
    int i = blockIdx.x * 256 + threadIdx.x;
    if (i < E) {
        int p = atomicAdd(&cursor[recv[i]], 1);
        perm[p] = i;
    }
}

// ---------------- edge-parallel radial MLP ----------------
// thread-per-edge; weights are wave-uniform -> scalar loads; h fully in regs.
// Output: h2 packed bf16 pairs along k: h2out[e*32+j] = (h[2j], h[2j+1])
__global__ void k_mlp(const float* __restrict__ radial, const float* __restrict__ w0,
                      const float* __restrict__ w1, const float* __restrict__ w2,
                      unsigned int* __restrict__ h2out, int E)
{
    int e = blockIdx.x * 256 + threadIdx.x;
    if (e >= E) return;
    const float4* rp = (const float4*)(radial + (size_t)e * RDIM);
    float4 ra = rp[0], rb = rp[1];

    float a[64], b[64];
    #pragma unroll
    for (int j = 0; j < 64; j++) {
        float acc = ra.x * w0[j]       + ra.y * w0[64 + j]
                  + ra.z * w0[128 + j] + ra.w * w0[192 + j]
                  + rb.x * w0[256 + j] + rb.y * w0[320 + j]
                  + rb.z * w0[384 + j] + rb.w * w0[448 + j];
        a[j] = silu(acc * INV_SQRT8);
    }
    #pragma unroll
    for (int j = 0; j < 64; j++) b[j] = 0.f;
    #pragma unroll
    for (int k = 0; k < 64; k++) {
        float hk = a[k];
        #pragma unroll
        for (int j = 0; j < 64; j++) b[j] += hk * w1[k * 64 + j];
    }
    #pragma unroll
    for (int j = 0; j < 64; j++) { b[j] = silu(b[j] * 0.125f); a[j] = 0.f; }
    #pragma unroll
    for (int k = 0; k < 64; k++) {
        float hk = b[k];
        #pragma unroll
        for (int j = 0; j < 64; j++) a[j] += hk * w2[k * 64 + j];
    }
    unsigned int* o = h2out + (size_t)e * 32;
    #pragma unroll
    for (int j = 0; j < 32; j++) {
        float lo = silu(a[2 * j]     * 0.125f);
        float hi = silu(a[2 * j + 1] * 0.125f);
        o[j] = f2bf_bits(lo) | (f2bf_bits(hi) << 16);
    }
}

// ---------------- fused gather kernel ----------------
// One wave per node (dynamic ticket). Lane owns channels c=lane, lane+64.
// w3 in LDS packed bf16: w3a[k*64+lane] = uint4 (mq 0..3 pairs), w3b = mq 4.
// LDS = 64KB + 16KB = 80KB -> 2 blocks(512thr)/CU = 16 waves/CU.
__global__ __launch_bounds__(512, 4) void k_main(
    const float* __restrict__ vectors,
    const float* __restrict__ node_feats,
    const float* __restrict__ w3,
    const int*   __restrict__ senders,
    const int*   __restrict__ offsets,
    const int*   __restrict__ perm,
    const unsigned int* __restrict__ h2g,
    int* __restrict__ ctr,
    float* __restrict__ out, int N)
{
    __shared__ uint4        w3a[64 * 64];   // 65536 B
    __shared__ unsigned int w3b[64 * 64];   // 16384 B

    for (int idx = threadIdx.x; idx < 4096; idx += 512) {
        int lane = idx & 63, k = idx >> 6;
        const float* wr = w3 + k * 640;
        uint4 u;
        u.x = f2bf_bits(wr[lane])       | (f2bf_bits(wr[lane + 64])  << 16);
        u.y = f2bf_bits(wr[lane + 128]) | (f2bf_bits(wr[lane + 192]) << 16);
        u.z = f2bf_bits(wr[lane + 256]) | (f2bf_bits(wr[lane + 320]) << 16);
        u.w = f2bf_bits(wr[lane + 384]) | (f2bf_bits(wr[lane + 448]) << 16);
        w3a[idx] = u;
        w3b[idx] = f2bf_bits(wr[lane + 512]) | (f2bf_bits(wr[lane + 576]) << 16);
    }
    __syncthreads();

    const int lane = threadIdx.x & 63;

    while (true) {
        int t0 = 0;
        if (lane == 0) t0 = atomicAdd(ctr, 1);
        int node = __shfl(t0, 0, 64);
        if (node >= N) break;
        node = __builtin_amdgcn_readfirstlane(node);

        int beg = offsets[node];
        int end = offsets[node + 1];

        float aS[2]     = {0.f, 0.f};
        float aT0[2]    = {0.f, 0.f};
        float aV0[2][3] = {{0.f,0.f,0.f},{0.f,0.f,0.f}};
        float aV1[2][3] = {{0.f,0.f,0.f},{0.f,0.f,0.f}};
        float aV2[2][3] = {{0.f,0.f,0.f},{0.f,0.f,0.f}};

        for (int i0 = beg; i0 < end; i0 += 4) {
            int rem = end - i0;
            int nq = rem < 4 ? rem : 4;

            const unsigned int* hrow[4];
            float rnx[4], rny[4], rnz[4];
            int   snd[4];

            #pragma unroll
            for (int q = 0; q < 4; q++) {
                int e = (q < nq) ? perm[i0 + q] : perm[i0];
                e = __builtin_amdgcn_readfirstlane(e);
                hrow[q] = h2g + (size_t)e * 32;
                if (q < nq) {
                    float vx = vectors[(size_t)e * 3 + 0];
                    float vy = vectors[(size_t)e * 3 + 1];
                    float vz = vectors[(size_t)e * 3 + 2];
                    float inv = rsqrtf(vx * vx + vy * vy + vz * vz);
                    rnx[q] = vx * inv; rny[q] = vy * inv; rnz[q] = vz * inv;
                    snd[q] = senders[e];
                }
            }

            // ---- mix = h2 @ w3 (bf16), scalar h2 broadcast, no shfl ----
            float mixv[4][10];
            #pragma unroll
            for (int q = 0; q < 4; q++)
                #pragma unroll
                for (int m = 0; m < 10; m++) mixv[q][m] = 0.f;

            #pragma unroll 4
            for (int kp = 0; kp < 32; kp++) {
                float h0[4], h1[4];
                #pragma unroll
                for (int q = 0; q < 4; q++) {
                    unsigned int hu = hrow[q][kp];       // wave-uniform -> s_load
                    h0[q] = bflo(hu); h1[q] = bfhi(hu);
                }
                #pragma unroll
                for (int s = 0; s < 2; s++) {
                    int k = 2 * kp + s;
                    uint4 wa        = w3a[k * 64 + lane];
                    unsigned int wb = w3b[k * 64 + lane];
                    float wx0 = bflo(wa.x), wx1 = bfhi(wa.x);
                    float wy0 = bflo(wa.y), wy1 = bfhi(wa.y);
                    float wz0 = bflo(wa.z), wz1 = bfhi(wa.z);
                    float ww0 = bflo(wa.w), ww1 = bfhi(wa.w);
                    float wb0 = bflo(wb),   wb1 = bfhi(wb);
                    #pragma unroll
                    for (int q = 0; q < 4; q++) {
                        float h = s ? h1[q] : h0[q];
                        mixv[q][0] += wx0 * h; mixv[q][1] += wx1 * h;
                        mixv[q][2] += wy0 * h; mixv[q][3] += wy1 * h;
                        mixv[q][4] += wz0 * h; mixv[q][5] += wz1 * h;
                        mixv[q][6] += ww0 * h; mixv[q][7] += ww1 * h;
                        mixv[q][8] += wb0 * h; mixv[q][9] += wb1 * h;
                    }
                }
            }

            // ---- messages ----
            const float sc = 0.125f * INV_SQRT10;
            #pragma unroll
            for (int q = 0; q < 4; q++) {
                if (q < nq) {
                    const float* nf = node_feats + (size_t)snd[q] * NF;
                    #pragma unroll
                    for (int t = 0; t < 2; t++) {
                        int c = lane + 64 * t;
                        float ssv = nf[c];
                        float v0 = nf[CCH + 3 * c + 0];
                        float v1 = nf[CCH + 3 * c + 1];
                        float v2 = nf[CCH + 3 * c + 2];
                        float d = rnx[q] * v0 + rny[q] * v1 + rnz[q] * v2;

                        float m0 = mixv[q][t]     * sc;
                        float m1 = mixv[q][2 + t] * sc;
                        float m2 = mixv[q][4 + t] * sc;
                        float m3 = mixv[q][6 + t] * sc;
                        float m4 = mixv[q][8 + t] * sc * SQRT3;

                        aS[t]  += ssv * m0;
                        aT0[t] += d * m1;
                        aV0[t][0] += v0 * m2;
                        aV0[t][1] += v1 * m2;
                        aV0[t][2] += v2 * m2;
                        aV1[t][0] += ssv * rnx[q] * m3;
                        aV1[t][1] += ssv * rny[q] * m3;
                        aV1[t][2] += ssv * rnz[q] * m3;
                        aV2[t][0] += (d * rnx[q] - v0 * (1.f / 3.f)) * m4;
                        aV2[t][1] += (d * rny[q] - v1 * (1.f / 3.f)) * m4;
                        aV2[t][2] += (d * rnz[q] - v2 * (1.f / 3.f)) * m4;
                    }
                }
            }
        }

        float* ob = out + (size_t)node * OUTF;
        #pragma unroll
        for (int t = 0; t < 2; t++) {
            int c = lane + 64 * t;
            ob[c]                = aS[t];
            ob[CCH + c]          = aT0[t];
            ob[256  + 3 * c + 0] = aV0[t][0];
            ob[256  + 3 * c + 1] = aV0[t][1];
            ob[256  + 3 * c + 2] = aV0[t][2];
            ob[640  + 3 * c + 0] = aV1[t][0];
            ob[640  + 3 * c + 1] = aV1[t][1];
            ob[640  + 3 * c + 2] = aV1[t][2];
            ob[1024 + 3 * c + 0] = aV2[t][0];
            ob[1024 + 3 * c + 1] = aV2[t][1];
            ob[1024 + 3 * c + 2] = aV2[t][2];
        }
    }
}

extern "C" void kernel_launch(void* const* d_in, const int* in_sizes, int n_in,
                              void* d_out, int out_size, void* d_ws, size_t ws_size,
                              hipStream_t stream) {
    const float* vectors    = (const float*)d_in[0];
    const float* node_feats = (const float*)d_in[1];
    const float* radial     = (const float*)d_in[2];
    const float* w0         = (const float*)d_in[3];
    const float* w1         = (const float*)d_in[4];
    const float* w2         = (const float*)d_in[5];
    const float* w3         = (const float*)d_in[6];
    const int*   senders    = (const int*)d_in[7];
    const int*   receivers  = (const int*)d_in[8];

    int E = in_sizes[0] / 3;
    int N = in_sizes[1] / NF;

    // ws layout (ints): counts[N] | ctr[1] | offsets[N+1] | cursor[N] | perm[E] | h2[E*32]
    int* counts  = (int*)d_ws;
    int* ctr     = counts + N;
    int* offsets = ctr + 1;
    int* cursor  = offsets + N + 1;
    int* perm    = cursor + N;
    unsigned int* h2 = (unsigned int*)(perm + E);

    k_zero<<<(N + 1 + 255) / 256, 256, 0, stream>>>(counts, N + 1);
    k_hist<<<(E + 255) / 256, 256, 0, stream>>>(receivers, counts, E);
    k_scan<<<1, 1024, 0, stream>>>(counts, offsets, cursor, N);
    k_perm<<<(E + 255) / 256, 256, 0, stream>>>(receivers, cursor, perm, E);
    k_mlp<<<(E + 255) / 256, 256, 0, stream>>>(radial, w0, w1, w2, h2, E);
    k_main<<<512, 512, 0, stream>>>(vectors, node_feats, w3, senders, offsets, perm,
                                    h2, ctr, (float*)d_out, N);
}

// Round 3
// 682.124 us; speedup vs baseline: 1.0503x; 1.0503x over previous
//
#include <hip/hip_runtime.h>

// Problem constants (fixed by reference)
#define CCH   128      // channels
#define NF    512      // node_feats row = C + 3C
#define OUTF  1408     // 2C + 3*3C
#define RDIM  8

#define INV_SQRT8  0.35355339059327373f
#define INV_SQRT10 0.31622776601683794f
#define SQRT3      1.7320508075688772f

typedef _Float16 half2_t __attribute__((ext_vector_type(2)));

__device__ __forceinline__ float silu(float x) {
    return x / (1.0f + __expf(-x));
}

__device__ __forceinline__ unsigned int packh2(float lo, float hi) {
    half2_t h = { (_Float16)lo, (_Float16)hi };
    return __builtin_bit_cast(unsigned int, h);
}

// (h.x*w.x + h.y*w.y + c) via v_dot2_f32_f16
__device__ __forceinline__ float dot2(unsigned int h, unsigned int w, float c) {
#if __has_builtin(__builtin_amdgcn_fdot2)
    return __builtin_amdgcn_fdot2(__builtin_bit_cast(half2_t, h),
                                  __builtin_bit_cast(half2_t, w), c, false);
#else
    half2_t a = __builtin_bit_cast(half2_t, h);
    half2_t b = __builtin_bit_cast(half2_t, w);
    return c + (float)a.x * (float)b.x + (float)a.y * (float)b.y;
#endif
}

// ---------------- CSR build ----------------
__global__ void k_zero(int* __restrict__ p, int n) {
    int i = blockIdx.x * 256 + threadIdx.x;
    if (i < n) p[i] = 0;
}

__global__ void k_hist(const int* __restrict__ recv, int* __restrict__ counts, int E) {
    int i = blockIdx.x * 256 + threadIdx.x;
    if (i < E) atomicAdd(&counts[recv[i]], 1);
}

// single-block exclusive scan over n, 1024 threads, wave-shuffle based
__global__ void k_scan(const int* __restrict__ counts, int* __restrict__ offsets,
                       int* __restrict__ cursor, int n) {
    __shared__ int wsum[16];
    int t = threadIdx.x;
    int lane = t & 63, wid = t >> 6;
    int carry = 0;
    for (int base = 0; base < n; base += 1024) {
        int i = base + t;
        int x = (i < n) ? counts[i] : 0;
        int s = x;
        #pragma unroll
        for (int off = 1; off < 64; off <<= 1) {
            int v = __shfl_up(s, off, 64);
            if (lane >= off) s += v;
        }
        if (lane == 63) wsum[wid] = s;
        __syncthreads();
        if (wid == 0) {
            int v = (lane < 16) ? wsum[lane] : 0;
            #pragma unroll
            for (int off = 1; off < 16; off <<= 1) {
                int u = __shfl_up(v, off, 64);
                if (lane >= off) v += u;
            }
            if (lane < 16) wsum[lane] = v;
        }
        __syncthreads();
        int excl_wave = (wid > 0) ? wsum[wid - 1] : 0;
        int incl = s + excl_wave;
        if (i < n) {
            int ex = carry + incl - x;
            offsets[i] = ex;
            cursor[i]  = ex;
        }
        carry += wsum[15];
        __syncthreads();
    }
    if (t == 0) offsets[n] = carry;
}

__global__ void k_perm(const int* __restrict__ recv, int* __restrict__ cursor,
                       int* __restrict__ perm, int E) {
    int i = blockIdx.x * 256 + threadIdx.x;
    if (i < E) {
        int p = atomicAdd(&cursor[recv[i]], 1);
        perm[p] = i;
    }
}

// ---------------- edge-parallel radial MLP ----------------
// thread-per-edge; weights wave-uniform -> s_load; h fully in regs.
// __launch_bounds__(256,1): VGPR cap 512 so a[64]+b[64] stay in registers
// (round-2 regression: default cap 64 VGPR -> 350 MB scratch spill traffic).
// Output: h2 packed f16 pairs along k: h2out[e*32+kp] = (h[2kp], h[2kp+1])
__global__ __launch_bounds__(256, 1) void k_mlp(
    const float* __restrict__ radial, const float* __restrict__ w0,
    const float* __restrict__ w1, const float* __restrict__ w2,
    unsigned int* __restrict__ h2out, int E)
{
    int e = blockIdx.x * 256 + threadIdx.x;
    if (e >= E) return;
    const float4* rp = (const float4*)(radial + (size_t)e * RDIM);
    float4 ra = rp[0], rb = rp[1];

    float a[64], b[64];
    #pragma unroll
    for (int j = 0; j < 64; j++) {
        float acc = ra.x * w0[j]       + ra.y * w0[64 + j]
                  + ra.z * w0[128 + j] + ra.w * w0[192 + j]
                  + rb.x * w0[256 + j] + rb.y * w0[320 + j]
                  + rb.z * w0[384 + j] + rb.w * w0[448 + j];
        a[j] = silu(acc * INV_SQRT8);
    }
    #pragma unroll
    for (int j = 0; j < 64; j++) b[j] = 0.f;
    #pragma unroll
    for (int k = 0; k < 64; k++) {
        float hk = a[k];
        #pragma unroll
        for (int j = 0; j < 64; j++) b[j] += hk * w1[k * 64 + j];
    }
    #pragma unroll
    for (int j = 0; j < 64; j++) { b[j] = silu(b[j] * 0.125f); a[j] = 0.f; }
    #pragma unroll
    for (int k = 0; k < 64; k++) {
        float hk = b[k];
        #pragma unroll
        for (int j = 0; j < 64; j++) a[j] += hk * w2[k * 64 + j];
    }
    unsigned int* o = h2out + (size_t)e * 32;
    #pragma unroll
    for (int kp = 0; kp < 32; kp++) {
        float lo = silu(a[2 * kp]     * 0.125f);
        float hi = silu(a[2 * kp + 1] * 0.125f);
        o[kp] = packh2(lo, hi);
    }
}

// ---------------- fused gather kernel ----------------
// One wave per node (dynamic ticket). Lane owns channels c=lane, lane+64.
// w3 in LDS as f16 k-pairs: entry[kp*64+lane] packs (w3[2kp][c_m], w3[2kp+1][c_m])
// for m-groups: wA = m0..3 (uint4), wB = m4..7 (uint4), wC = m8..9 (uint2).
// LDS = 32+32+16 = 80 KB -> 2 blocks(512thr)/CU = 16 waves/CU.
// stride-16B uint4 LDS reads showed SQ_LDS_BANK_CONFLICT==0 in round 2.
__global__ __launch_bounds__(512, 4) void k_main(
    const float* __restrict__ vectors,
    const float* __restrict__ node_feats,
    const float* __restrict__ w3,
    const int*   __restrict__ senders,
    const int*   __restrict__ offsets,
    const int*   __restrict__ perm,
    const unsigned int* __restrict__ h2g,
    int* __restrict__ ctr,
    float* __restrict__ out, int N)
{
    __shared__ uint4 wA[32 * 64];   // 32768 B
    __shared__ uint4 wB[32 * 64];   // 32768 B
    __shared__ uint2 wC[32 * 64];   // 16384 B

    for (int idx = threadIdx.x; idx < 32 * 64; idx += 512) {
        int lane = idx & 63, kp = idx >> 6;
        const float* r0 = w3 + (2 * kp) * 640;
        const float* r1 = r0 + 640;
        uint4 A, B; uint2 Cc;
        A.x = packh2(r0[lane],       r1[lane]);
        A.y = packh2(r0[lane + 64],  r1[lane + 64]);
        A.z = packh2(r0[lane + 128], r1[lane + 128]);
        A.w = packh2(r0[lane + 192], r1[lane + 192]);
        B.x = packh2(r0[lane + 256], r1[lane + 256]);
        B.y = packh2(r0[lane + 320], r1[lane + 320]);
        B.z = packh2(r0[lane + 384], r1[lane + 384]);
        B.w = packh2(r0[lane + 448], r1[lane + 448]);
        Cc.x = packh2(r0[lane + 512], r1[lane + 512]);
        Cc.y = packh2(r0[lane + 576], r1[lane + 576]);
        wA[idx] = A; wB[idx] = B; wC[idx] = Cc;
    }
    __syncthreads();

    const int lane = threadIdx.x & 63;

    while (true) {
        int t0 = 0;
        if (lane == 0) t0 = atomicAdd(ctr, 1);
        int node = __shfl(t0, 0, 64);
        if (node >= N) break;
        node = __builtin_amdgcn_readfirstlane(node);

        int beg = offsets[node];
        int end = offsets[node + 1];

        float aS[2]     = {0.f, 0.f};
        float aT0[2]    = {0.f, 0.f};
        float aV0[2][3] = {{0.f,0.f,0.f},{0.f,0.f,0.f}};
        float aV1[2][3] = {{0.f,0.f,0.f},{0.f,0.f,0.f}};
        float aV2[2][3] = {{0.f,0.f,0.f},{0.f,0.f,0.f}};

        for (int i0 = beg; i0 < end; i0 += 4) {
            int rem = end - i0;
            int nq = rem < 4 ? rem : 4;

            const unsigned int* hrow[4];
            float rnx[4], rny[4], rnz[4];
            int   snd[4];

            #pragma unroll
            for (int q = 0; q < 4; q++) {
                int e = (q < nq) ? perm[i0 + q] : perm[i0];
                e = __builtin_amdgcn_readfirstlane(e);
                hrow[q] = h2g + (size_t)e * 32;
                if (q < nq) {
                    float vx = vectors[(size_t)e * 3 + 0];
                    float vy = vectors[(size_t)e * 3 + 1];
                    float vz = vectors[(size_t)e * 3 + 2];
                    float inv = rsqrtf(vx * vx + vy * vy + vz * vz);
                    rnx[q] = vx * inv; rny[q] = vy * inv; rnz[q] = vz * inv;
                    snd[q] = senders[e];
                }
            }

            // ---- mix = h2 @ w3 via v_dot2_f32_f16, scalar h2 broadcast ----
            float mixv[4][10];
            #pragma unroll
            for (int q = 0; q < 4; q++)
                #pragma unroll
                for (int m = 0; m < 10; m++) mixv[q][m] = 0.f;

            #pragma unroll 4
            for (int kp = 0; kp < 32; kp++) {
                unsigned int hq[4];
                #pragma unroll
                for (int q = 0; q < 4; q++) hq[q] = hrow[q][kp];  // wave-uniform
                uint4 A  = wA[kp * 64 + lane];
                uint4 B  = wB[kp * 64 + lane];
                uint2 Cc = wC[kp * 64 + lane];
                #pragma unroll
                for (int q = 0; q < 4; q++) {
                    unsigned int h = hq[q];
                    mixv[q][0] = dot2(h, A.x,  mixv[q][0]);
                    mixv[q][1] = dot2(h, A.y,  mixv[q][1]);
                    mixv[q][2] = dot2(h, A.z,  mixv[q][2]);
                    mixv[q][3] = dot2(h, A.w,  mixv[q][3]);
                    mixv[q][4] = dot2(h, B.x,  mixv[q][4]);
                    mixv[q][5] = dot2(h, B.y,  mixv[q][5]);
                    mixv[q][6] = dot2(h, B.z,  mixv[q][6]);
                    mixv[q][7] = dot2(h, B.w,  mixv[q][7]);
                    mixv[q][8] = dot2(h, Cc.x, mixv[q][8]);
                    mixv[q][9] = dot2(h, Cc.y, mixv[q][9]);
                }
            }

            // ---- messages ----
            const float sc = 0.125f * INV_SQRT10;
            #pragma unroll
            for (int q = 0; q < 4; q++) {
                if (q < nq) {
                    const float* nf = node_feats + (size_t)snd[q] * NF;
                    #pragma unroll
                    for (int t = 0; t < 2; t++) {
                        int c = lane + 64 * t;
                        float ssv = nf[c];
                        float v0 = nf[CCH + 3 * c + 0];
                        float v1 = nf[CCH + 3 * c + 1];
                        float v2 = nf[CCH + 3 * c + 2];
                        float d = rnx[q] * v0 + rny[q] * v1 + rnz[q] * v2;

                        float m0 = mixv[q][t]     * sc;
                        float m1 = mixv[q][2 + t] * sc;
                        float m2 = mixv[q][4 + t] * sc;
                        float m3 = mixv[q][6 + t] * sc;
                        float m4 = mixv[q][8 + t] * sc * SQRT3;

                        aS[t]  += ssv * m0;
                        aT0[t] += d * m1;
                        aV0[t][0] += v0 * m2;
                        aV0[t][1] += v1 * m2;
                        aV0[t][2] += v2 * m2;
                        aV1[t][0] += ssv * rnx[q] * m3;
                        aV1[t][1] += ssv * rny[q] * m3;
                        aV1[t][2] += ssv * rnz[q] * m3;
                        aV2[t][0] += (d * rnx[q] - v0 * (1.f / 3.f)) * m4;
                        aV2[t][1] += (d * rny[q] - v1 * (1.f / 3.f)) * m4;
                        aV2[t][2] += (d * rnz[q] - v2 * (1.f / 3.f)) * m4;
                    }
                }
            }
        }

        float* ob = out + (size_t)node * OUTF;
        #pragma unroll
        for (int t = 0; t < 2; t++) {
            int c = lane + 64 * t;
            ob[c]                = aS[t];
            ob[CCH + c]          = aT0[t];
            ob[256  + 3 * c + 0] = aV0[t][0];
            ob[256  + 3 * c + 1] = aV0[t][1];
            ob[256  + 3 * c + 2] = aV0[t][2];
            ob[640  + 3 * c + 0] = aV1[t][0];
            ob[640  + 3 * c + 1] = aV1[t][1];
            ob[640  + 3 * c + 2] = aV1[t][2];
            ob[1024 + 3 * c + 0] = aV2[t][0];
            ob[1024 + 3 * c + 1] = aV2[t][1];
            ob[1024 + 3 * c + 2] = aV2[t][2];
        }
    }
}

extern "C" void kernel_launch(void* const* d_in, const int* in_sizes, int n_in,
                              void* d_out, int out_size, void* d_ws, size_t ws_size,
                              hipStream_t stream) {
    const float* vectors    = (const float*)d_in[0];
    const float* node_feats = (const float*)d_in[1];
    const float* radial     = (const float*)d_in[2];
    const float* w0         = (const float*)d_in[3];
    const float* w1         = (const float*)d_in[4];
    const float* w2         = (const float*)d_in[5];
    const float* w3         = (const float*)d_in[6];
    const int*   senders    = (const int*)d_in[7];
    const int*   receivers  = (const int*)d_in[8];

    int E = in_sizes[0] / 3;
    int N = in_sizes[1] / NF;

    // ws layout (ints): counts[N] | ctr[1] | offsets[N+1] | cursor[N] | perm[E] | h2[E*32]
    int* counts  = (int*)d_ws;
    int* ctr     = counts + N;
    int* offsets = ctr + 1;
    int* cursor  = offsets + N + 1;
    int* perm    = cursor + N;
    unsigned int* h2 = (unsigned int*)(perm + E);

    k_zero<<<(N + 1 + 255) / 256, 256, 0, stream>>>(counts, N + 1);
    k_hist<<<(E + 255) / 256, 256, 0, stream>>>(receivers, counts, E);
    k_scan<<<1, 1024, 0, stream>>>(counts, offsets, cursor, N);
    k_perm<<<(E + 255) / 256, 256, 0, stream>>>(receivers, cursor, perm, E);
    k_mlp<<<(E + 255) / 256, 256, 0, stream>>>(radial, w0, w1, w2, h2, E);
    k_main<<<512, 512, 0, stream>>>(vectors, node_feats, w3, senders, offsets, perm,
                                    h2, ctr, (float*)d_out, N);
}

// Round 4
// 295.371 us; speedup vs baseline: 2.4255x; 2.3094x over previous
//
#include <hip/hip_runtime.h>

// Problem constants (fixed by reference)
#define CCH   128      // channels
#define NF    512      // node_feats row = C + 3C
#define OUTF  1408     // 2C + 3*3C
#define RDIM  8

#define INV_SQRT8  0.35355339059327373f
#define INV_SQRT10 0.31622776601683794f
#define SQRT3      1.7320508075688772f

typedef _Float16 half2_t __attribute__((ext_vector_type(2)));

__device__ __forceinline__ float silu(float x) {
    return x / (1.0f + __expf(-x));
}

__device__ __forceinline__ unsigned int packh2(float lo, float hi) {
    half2_t h = { (_Float16)lo, (_Float16)hi };
    return __builtin_bit_cast(unsigned int, h);
}
__device__ __forceinline__ float h2lo(unsigned int u) {
    return (float)__builtin_bit_cast(half2_t, u).x;
}
__device__ __forceinline__ float h2hi(unsigned int u) {
    return (float)__builtin_bit_cast(half2_t, u).y;
}

// (h.x*w.x + h.y*w.y + c) via v_dot2_f32_f16
__device__ __forceinline__ float dot2(unsigned int h, unsigned int w, float c) {
#if __has_builtin(__builtin_amdgcn_fdot2)
    return __builtin_amdgcn_fdot2(__builtin_bit_cast(half2_t, h),
                                  __builtin_bit_cast(half2_t, w), c, false);
#else
    half2_t a = __builtin_bit_cast(half2_t, h);
    half2_t b = __builtin_bit_cast(half2_t, w);
    return c + (float)a.x * (float)b.x + (float)a.y * (float)b.y;
#endif
}

// ---------------- CSR build ----------------
__global__ void k_zero(int* __restrict__ p, int n) {
    int i = blockIdx.x * 256 + threadIdx.x;
    if (i < n) p[i] = 0;
}

__global__ void k_hist(const int* __restrict__ recv, int* __restrict__ counts, int E) {
    int i = blockIdx.x * 256 + threadIdx.x;
    if (i < E) atomicAdd(&counts[recv[i]], 1);
}

__global__ void k_scan(const int* __restrict__ counts, int* __restrict__ offsets,
                       int* __restrict__ cursor, int n) {
    __shared__ int wsum[16];
    int t = threadIdx.x;
    int lane = t & 63, wid = t >> 6;
    int carry = 0;
    for (int base = 0; base < n; base += 1024) {
        int i = base + t;
        int x = (i < n) ? counts[i] : 0;
        int s = x;
        #pragma unroll
        for (int off = 1; off < 64; off <<= 1) {
            int v = __shfl_up(s, off, 64);
            if (lane >= off) s += v;
        }
        if (lane == 63) wsum[wid] = s;
        __syncthreads();
        if (wid == 0) {
            int v = (lane < 16) ? wsum[lane] : 0;
            #pragma unroll
            for (int off = 1; off < 16; off <<= 1) {
                int u = __shfl_up(v, off, 64);
                if (lane >= off) v += u;
            }
            if (lane < 16) wsum[lane] = v;
        }
        __syncthreads();
        int excl_wave = (wid > 0) ? wsum[wid - 1] : 0;
        int incl = s + excl_wave;
        if (i < n) {
            int ex = carry + incl - x;
            offsets[i] = ex;
            cursor[i]  = ex;
        }
        carry += wsum[15];
        __syncthreads();
    }
    if (t == 0) offsets[n] = carry;
}

__global__ void k_perm(const int* __restrict__ recv, int* __restrict__ cursor,
                       int* __restrict__ perm, int E) {
    int i = blockIdx.x * 256 + threadIdx.x;
    if (i < E) {
        int p = atomicAdd(&cursor[recv[i]], 1);
        perm[p] = i;
    }
}

// ---------------- cooperative radial MLP ----------------
// Wave handles 4 edges; lane owns hidden unit j. h exchanged through per-wave
// LDS (f16), weights in LDS as f16 k-pairs for v_dot2_f32_f16.
// Grid = E/16 blocks of 256 -> ~24 waves/SIMD (round-3 k_mlp had 1.5 -> 400us).
// Output: h2out[e*64+j] f16 (consecutive pairs = uint k-pairs for k_mix/fused).
__global__ __launch_bounds__(256, 4) void k_mlp2(
    const float* __restrict__ radial,
    const float* __restrict__ w0, const float* __restrict__ w1,
    const float* __restrict__ w2, _Float16* __restrict__ h2out, int E)
{
    __shared__ float        w0s[8 * 64];     // 2 KB
    __shared__ unsigned int w1p[32 * 64];    // 8 KB
    __shared__ unsigned int w2p[32 * 64];    // 8 KB
    __shared__ _Float16     hs[4][4][64];    // [wave][edge][unit] 2 KB

    for (int idx = threadIdx.x; idx < 512; idx += 256) w0s[idx] = w0[idx];
    for (int idx = threadIdx.x; idx < 2048; idx += 256) {
        int j = idx & 63, kp = idx >> 6;
        w1p[idx] = packh2(w1[(2 * kp) * 64 + j], w1[(2 * kp + 1) * 64 + j]);
        w2p[idx] = packh2(w2[(2 * kp) * 64 + j], w2[(2 * kp + 1) * 64 + j]);
    }
    __syncthreads();

    const int lane = threadIdx.x & 63;
    const int wid  = threadIdx.x >> 6;
    unsigned int* hsu = (unsigned int*)&hs[wid][0][0];   // [q*32 + kp]

    int e0 = (blockIdx.x * 4 + wid) * 4;

    // L0: h0[q][j] = silu( (r[q] . w0[:,j]) / sqrt(8) )
    float w0r[8];
    #pragma unroll
    for (int k = 0; k < 8; k++) w0r[k] = w0s[k * 64 + lane];
    #pragma unroll
    for (int q = 0; q < 4; q++) {
        int e = e0 + q; if (e >= E) e = E - 1;   // clamp (uniform flow for barriers)
        const float* r = radial + (size_t)e * RDIM;
        float acc = 0.f;
        #pragma unroll
        for (int k = 0; k < 8; k++) acc += r[k] * w0r[k];
        hs[wid][q][lane] = (_Float16)silu(acc * INV_SQRT8);
    }
    __syncthreads();

    // L1
    float acc1[4] = {0.f, 0.f, 0.f, 0.f};
    #pragma unroll 4
    for (int kp = 0; kp < 32; kp++) {
        unsigned int w = w1p[kp * 64 + lane];
        #pragma unroll
        for (int q = 0; q < 4; q++) acc1[q] = dot2(hsu[q * 32 + kp], w, acc1[q]);
    }
    __syncthreads();
    #pragma unroll
    for (int q = 0; q < 4; q++) hs[wid][q][lane] = (_Float16)silu(acc1[q] * 0.125f);
    __syncthreads();

    // L2
    float acc2[4] = {0.f, 0.f, 0.f, 0.f};
    #pragma unroll 4
    for (int kp = 0; kp < 32; kp++) {
        unsigned int w = w2p[kp * 64 + lane];
        #pragma unroll
        for (int q = 0; q < 4; q++) acc2[q] = dot2(hsu[q * 32 + kp], w, acc2[q]);
    }
    #pragma unroll
    for (int q = 0; q < 4; q++) {
        int e = e0 + q;
        if (e < E) h2out[(size_t)e * 64 + lane] = (_Float16)silu(acc2[q] * 0.125f);
    }
}

// ---------------- edge-parallel mix GEMM (materializing) ----------------
// Wave per 4 consecutive edges, grid-stride. w3 in LDS (80 KB) as f16 k-pairs.
// Writes pre-scaled mix as packed f16 col-pairs: mixp[e*320 + m'*64 + lane]
// = (mix[col lane+128m'], mix[col lane+128m'+64]) * sc (m'=4 also * sqrt3).
__global__ __launch_bounds__(512, 4) void k_mix(
    const float* __restrict__ w3,
    const unsigned int* __restrict__ h2g,    // f16 pairs view of h2out
    unsigned int* __restrict__ mixp, int E)
{
    __shared__ uint4 wA[32 * 64];   // 32768 B
    __shared__ uint4 wB[32 * 64];   // 32768 B
    __shared__ uint2 wC[32 * 64];   // 16384 B

    for (int idx = threadIdx.x; idx < 32 * 64; idx += 512) {
        int lane = idx & 63, kp = idx >> 6;
        const float* r0 = w3 + (2 * kp) * 640;
        const float* r1 = r0 + 640;
        uint4 A, B; uint2 Cc;
        A.x = packh2(r0[lane],       r1[lane]);
        A.y = packh2(r0[lane + 64],  r1[lane + 64]);
        A.z = packh2(r0[lane + 128], r1[lane + 128]);
        A.w = packh2(r0[lane + 192], r1[lane + 192]);
        B.x = packh2(r0[lane + 256], r1[lane + 256]);
        B.y = packh2(r0[lane + 320], r1[lane + 320]);
        B.z = packh2(r0[lane + 384], r1[lane + 384]);
        B.w = packh2(r0[lane + 448], r1[lane + 448]);
        Cc.x = packh2(r0[lane + 512], r1[lane + 512]);
        Cc.y = packh2(r0[lane + 576], r1[lane + 576]);
        wA[idx] = A; wB[idx] = B; wC[idx] = Cc;
    }
    __syncthreads();

    const int lane = threadIdx.x & 63;
    int wave = blockIdx.x * 8 + (threadIdx.x >> 6);
    int nwaves = gridDim.x * 8;
    int nquads = (E + 3) >> 2;
    const float sc = 0.125f * INV_SQRT10;

    for (int t = wave; t < nquads; t += nwaves) {
        int e0 = t * 4;
        const unsigned int* hp[4];
        #pragma unroll
        for (int q = 0; q < 4; q++) {
            int e = e0 + q; if (e >= E) e = E - 1;
            hp[q] = h2g + (size_t)e * 32;
        }

        float mixv[4][10];
        #pragma unroll
        for (int q = 0; q < 4; q++)
            #pragma unroll
            for (int m = 0; m < 10; m++) mixv[q][m] = 0.f;

        #pragma unroll 4
        for (int kp = 0; kp < 32; kp++) {
            unsigned int hq[4];
            #pragma unroll
            for (int q = 0; q < 4; q++) hq[q] = hp[q][kp];   // wave-uniform s_load
            uint4 A  = wA[kp * 64 + lane];
            uint4 B  = wB[kp * 64 + lane];
            uint2 Cc = wC[kp * 64 + lane];
            #pragma unroll
            for (int q = 0; q < 4; q++) {
                unsigned int h = hq[q];
                mixv[q][0] = dot2(h, A.x,  mixv[q][0]);
                mixv[q][1] = dot2(h, A.y,  mixv[q][1]);
                mixv[q][2] = dot2(h, A.z,  mixv[q][2]);
                mixv[q][3] = dot2(h, A.w,  mixv[q][3]);
                mixv[q][4] = dot2(h, B.x,  mixv[q][4]);
                mixv[q][5] = dot2(h, B.y,  mixv[q][5]);
                mixv[q][6] = dot2(h, B.z,  mixv[q][6]);
                mixv[q][7] = dot2(h, B.w,  mixv[q][7]);
                mixv[q][8] = dot2(h, Cc.x, mixv[q][8]);
                mixv[q][9] = dot2(h, Cc.y, mixv[q][9]);
            }
        }

        #pragma unroll
        for (int q = 0; q < 4; q++) {
            int e = e0 + q;
            if (e < E) {
                unsigned int* mp = mixp + (size_t)e * 320 + lane;
                mp[0]   = packh2(mixv[q][0] * sc,         mixv[q][1] * sc);
                mp[64]  = packh2(mixv[q][2] * sc,         mixv[q][3] * sc);
                mp[128] = packh2(mixv[q][4] * sc,         mixv[q][5] * sc);
                mp[192] = packh2(mixv[q][6] * sc,         mixv[q][7] * sc);
                mp[256] = packh2(mixv[q][8] * sc * SQRT3, mixv[q][9] * sc * SQRT3);
            }
        }
    }
}

// ---------------- lean gather (no LDS, no mix compute) ----------------
// Wave per node; per edge: 5 mix loads + 8 nf loads + ~60 FMA per lane.
__global__ __launch_bounds__(256, 4) void k_gather(
    const float* __restrict__ vectors,
    const float* __restrict__ node_feats,
    const int*   __restrict__ senders,
    const int*   __restrict__ offsets,
    const int*   __restrict__ perm,
    const unsigned int* __restrict__ mixp,
    float* __restrict__ out, int N)
{
    const int lane = threadIdx.x & 63;
    int node = blockIdx.x * 4 + (threadIdx.x >> 6);
    if (node >= N) return;

    int beg = offsets[node];
    int end = offsets[node + 1];

    float aS[2]     = {0.f, 0.f};
    float aT0[2]    = {0.f, 0.f};
    float aV0[2][3] = {{0.f,0.f,0.f},{0.f,0.f,0.f}};
    float aV1[2][3] = {{0.f,0.f,0.f},{0.f,0.f,0.f}};
    float aV2[2][3] = {{0.f,0.f,0.f},{0.f,0.f,0.f}};

    for (int i = beg; i < end; i++) {
        int e = perm[i];
        float vx = vectors[(size_t)e * 3 + 0];
        float vy = vectors[(size_t)e * 3 + 1];
        float vz = vectors[(size_t)e * 3 + 2];
        float inv = rsqrtf(vx * vx + vy * vy + vz * vz);
        float rx = vx * inv, ry = vy * inv, rz = vz * inv;
        int snd = senders[e];

        const unsigned int* mp = mixp + (size_t)e * 320 + lane;
        unsigned int u0 = mp[0], u1 = mp[64], u2 = mp[128], u3 = mp[192], u4 = mp[256];

        const float* nf = node_feats + (size_t)snd * NF;
        #pragma unroll
        for (int t = 0; t < 2; t++) {
            int c = lane + 64 * t;
            float ssv = nf[c];
            float v0 = nf[CCH + 3 * c + 0];
            float v1 = nf[CCH + 3 * c + 1];
            float v2 = nf[CCH + 3 * c + 2];
            float d = rx * v0 + ry * v1 + rz * v2;

            float m0 = t ? h2hi(u0) : h2lo(u0);
            float m1 = t ? h2hi(u1) : h2lo(u1);
            float m2 = t ? h2hi(u2) : h2lo(u2);
            float m3 = t ? h2hi(u3) : h2lo(u3);
            float m4 = t ? h2hi(u4) : h2lo(u4);

            aS[t]  += ssv * m0;
            aT0[t] += d * m1;
            aV0[t][0] += v0 * m2;
            aV0[t][1] += v1 * m2;
            aV0[t][2] += v2 * m2;
            aV1[t][0] += ssv * rx * m3;
            aV1[t][1] += ssv * ry * m3;
            aV1[t][2] += ssv * rz * m3;
            aV2[t][0] += (d * rx - v0 * (1.f / 3.f)) * m4;
            aV2[t][1] += (d * ry - v1 * (1.f / 3.f)) * m4;
            aV2[t][2] += (d * rz - v2 * (1.f / 3.f)) * m4;
        }
    }

    float* ob = out + (size_t)node * OUTF;
    #pragma unroll
    for (int t = 0; t < 2; t++) {
        int c = lane + 64 * t;
        ob[c]                = aS[t];
        ob[CCH + c]          = aT0[t];
        ob[256  + 3 * c + 0] = aV0[t][0];
        ob[256  + 3 * c + 1] = aV0[t][1];
        ob[256  + 3 * c + 2] = aV0[t][2];
        ob[640  + 3 * c + 0] = aV1[t][0];
        ob[640  + 3 * c + 1] = aV1[t][1];
        ob[640  + 3 * c + 2] = aV1[t][2];
        ob[1024 + 3 * c + 0] = aV2[t][0];
        ob[1024 + 3 * c + 1] = aV2[t][1];
        ob[1024 + 3 * c + 2] = aV2[t][2];
    }
}

// ---------------- fallback fused gather (round-3 k_main) ----------------
// Used only when ws_size can't hold mixp (needs ~142 MB).
__global__ __launch_bounds__(512, 4) void k_main_fused(
    const float* __restrict__ vectors,
    const float* __restrict__ node_feats,
    const float* __restrict__ w3,
    const int*   __restrict__ senders,
    const int*   __restrict__ offsets,
    const int*   __restrict__ perm,
    const unsigned int* __restrict__ h2g,
    int* __restrict__ ctr,
    float* __restrict__ out, int N)
{
    __shared__ uint4 wA[32 * 64];
    __shared__ uint4 wB[32 * 64];
    __shared__ uint2 wC[32 * 64];

    for (int idx = threadIdx.x; idx < 32 * 64; idx += 512) {
        int lane = idx & 63, kp = idx >> 6;
        const float* r0 = w3 + (2 * kp) * 640;
        const float* r1 = r0 + 640;
        uint4 A, B; uint2 Cc;
        A.x = packh2(r0[lane],       r1[lane]);
        A.y = packh2(r0[lane + 64],  r1[lane + 64]);
        A.z = packh2(r0[lane + 128], r1[lane + 128]);
        A.w = packh2(r0[lane + 192], r1[lane + 192]);
        B.x = packh2(r0[lane + 256], r1[lane + 256]);
        B.y = packh2(r0[lane + 320], r1[lane + 320]);
        B.z = packh2(r0[lane + 384], r1[lane + 384]);
        B.w = packh2(r0[lane + 448], r1[lane + 448]);
        Cc.x = packh2(r0[lane + 512], r1[lane + 512]);
        Cc.y = packh2(r0[lane + 576], r1[lane + 576]);
        wA[idx] = A; wB[idx] = B; wC[idx] = Cc;
    }
    __syncthreads();

    const int lane = threadIdx.x & 63;

    while (true) {
        int t0 = 0;
        if (lane == 0) t0 = atomicAdd(ctr, 1);
        int node = __shfl(t0, 0, 64);
        if (node >= N) break;
        node = __builtin_amdgcn_readfirstlane(node);

        int beg = offsets[node];
        int end = offsets[node + 1];

        float aS[2]     = {0.f, 0.f};
        float aT0[2]    = {0.f, 0.f};
        float aV0[2][3] = {{0.f,0.f,0.f},{0.f,0.f,0.f}};
        float aV1[2][3] = {{0.f,0.f,0.f},{0.f,0.f,0.f}};
        float aV2[2][3] = {{0.f,0.f,0.f},{0.f,0.f,0.f}};

        for (int i0 = beg; i0 < end; i0 += 4) {
            int rem = end - i0;
            int nq = rem < 4 ? rem : 4;

            const unsigned int* hrow[4];
            float rnx[4], rny[4], rnz[4];
            int   snd[4];

            #pragma unroll
            for (int q = 0; q < 4; q++) {
                int e = (q < nq) ? perm[i0 + q] : perm[i0];
                e = __builtin_amdgcn_readfirstlane(e);
                hrow[q] = h2g + (size_t)e * 32;
                if (q < nq) {
                    float vx = vectors[(size_t)e * 3 + 0];
                    float vy = vectors[(size_t)e * 3 + 1];
                    float vz = vectors[(size_t)e * 3 + 2];
                    float inv = rsqrtf(vx * vx + vy * vy + vz * vz);
                    rnx[q] = vx * inv; rny[q] = vy * inv; rnz[q] = vz * inv;
                    snd[q] = senders[e];
                }
            }

            float mixv[4][10];
            #pragma unroll
            for (int q = 0; q < 4; q++)
                #pragma unroll
                for (int m = 0; m < 10; m++) mixv[q][m] = 0.f;

            #pragma unroll 4
            for (int kp = 0; kp < 32; kp++) {
                unsigned int hq[4];
                #pragma unroll
                for (int q = 0; q < 4; q++) hq[q] = hrow[q][kp];
                uint4 A  = wA[kp * 64 + lane];
                uint4 B  = wB[kp * 64 + lane];
                uint2 Cc = wC[kp * 64 + lane];
                #pragma unroll
                for (int q = 0; q < 4; q++) {
                    unsigned int h = hq[q];
                    mixv[q][0] = dot2(h, A.x,  mixv[q][0]);
                    mixv[q][1] = dot2(h, A.y,  mixv[q][1]);
                    mixv[q][2] = dot2(h, A.z,  mixv[q][2]);
                    mixv[q][3] = dot2(h, A.w,  mixv[q][3]);
                    mixv[q][4] = dot2(h, B.x,  mixv[q][4]);
                    mixv[q][5] = dot2(h, B.y,  mixv[q][5]);
                    mixv[q][6] = dot2(h, B.z,  mixv[q][6]);
                    mixv[q][7] = dot2(h, B.w,  mixv[q][7]);
                    mixv[q][8] = dot2(h, Cc.x, mixv[q][8]);
                    mixv[q][9] = dot2(h, Cc.y, mixv[q][9]);
                }
            }

            const float sc = 0.125f * INV_SQRT10;
            #pragma unroll
            for (int q = 0; q < 4; q++) {
                if (q < nq) {
                    const float* nf = node_feats + (size_t)snd[q] * NF;
                    #pragma unroll
                    for (int t = 0; t < 2; t++) {
                        int c = lane + 64 * t;
                        float ssv = nf[c];
                        float v0 = nf[CCH + 3 * c + 0];
                        float v1 = nf[CCH + 3 * c + 1];
                        float v2 = nf[CCH + 3 * c + 2];
                        float d = rnx[q] * v0 + rny[q] * v1 + rnz[q] * v2;

                        float m0 = mixv[q][t]     * sc;
                        float m1 = mixv[q][2 + t] * sc;
                        float m2 = mixv[q][4 + t] * sc;
                        float m3 = mixv[q][6 + t] * sc;
                        float m4 = mixv[q][8 + t] * sc * SQRT3;

                        aS[t]  += ssv * m0;
                        aT0[t] += d * m1;
                        aV0[t][0] += v0 * m2;
                        aV0[t][1] += v1 * m2;
                        aV0[t][2] += v2 * m2;
                        aV1[t][0] += ssv * rnx[q] * m3;
                        aV1[t][1] += ssv * rny[q] * m3;
                        aV1[t][2] += ssv * rnz[q] * m3;
                        aV2[t][0] += (d * rnx[q] - v0 * (1.f / 3.f)) * m4;
                        aV2[t][1] += (d * rny[q] - v1 * (1.f / 3.f)) * m4;
                        aV2[t][2] += (d * rnz[q] - v2 * (1.f / 3.f)) * m4;
                    }
                }
            }
        }

        float* ob = out + (size_t)node * OUTF;
        #pragma unroll
        for (int t = 0; t < 2; t++) {
            int c = lane + 64 * t;
            ob[c]                = aS[t];
            ob[CCH + c]          = aT0[t];
            ob[256  + 3 * c + 0] = aV0[t][0];
            ob[256  + 3 * c + 1] = aV0[t][1];
            ob[256  + 3 * c + 2] = aV0[t][2];
            ob[640  + 3 * c + 0] = aV1[t][0];
            ob[640  + 3 * c + 1] = aV1[t][1];
            ob[640  + 3 * c + 2] = aV1[t][2];
            ob[1024 + 3 * c + 0] = aV2[t][0];
            ob[1024 + 3 * c + 1] = aV2[t][1];
            ob[1024 + 3 * c + 2] = aV2[t][2];
        }
    }
}

extern "C" void kernel_launch(void* const* d_in, const int* in_sizes, int n_in,
                              void* d_out, int out_size, void* d_ws, size_t ws_size,
                              hipStream_t stream) {
    const float* vectors    = (const float*)d_in[0];
    const float* node_feats = (const float*)d_in[1];
    const float* radial     = (const float*)d_in[2];
    const float* w0         = (const float*)d_in[3];
    const float* w1         = (const float*)d_in[4];
    const float* w2         = (const float*)d_in[5];
    const float* w3         = (const float*)d_in[6];
    const int*   senders    = (const int*)d_in[7];
    const int*   receivers  = (const int*)d_in[8];

    int E = in_sizes[0] / 3;
    int N = in_sizes[1] / NF;

    // ws layout (4-byte units): mixp[E*320] | h2[E*32] | counts[N] | ctr[1] |
    //                           offsets[N+1] | cursor[N] | perm[E]
    size_t small_elems = (size_t)E * 32 + N + 1 + (N + 1) + N + E;
    size_t full_elems  = (size_t)E * 320 + small_elems;
    bool big = ws_size >= full_elems * 4;

    unsigned int* mixp = (unsigned int*)d_ws;
    unsigned int* h2u  = mixp + (big ? (size_t)E * 320 : 0);
    int* counts  = (int*)(h2u + (size_t)E * 32);
    int* ctr     = counts + N;
    int* offsets = ctr + 1;
    int* cursor  = offsets + N + 1;
    int* perm    = cursor + N;
    _Float16* h2f = (_Float16*)h2u;

    k_zero<<<(N + 1 + 255) / 256, 256, 0, stream>>>(counts, N + 1);
    k_hist<<<(E + 255) / 256, 256, 0, stream>>>(receivers, counts, E);
    k_scan<<<1, 1024, 0, stream>>>(counts, offsets, cursor, N);
    k_perm<<<(E + 255) / 256, 256, 0, stream>>>(receivers, cursor, perm, E);
    k_mlp2<<<(E + 15) / 16, 256, 0, stream>>>(radial, w0, w1, w2, h2f, E);

    if (big) {
        k_mix<<<512, 512, 0, stream>>>(w3, h2u, mixp, E);
        k_gather<<<(N + 3) / 4, 256, 0, stream>>>(vectors, node_feats, senders,
                                                  offsets, perm, mixp,
                                                  (float*)d_out, N);
    } else {
        k_main_fused<<<512, 512, 0, stream>>>(vectors, node_feats, w3, senders,
                                              offsets, perm, h2u, ctr,
                                              (float*)d_out, N);
    }
}